// Round 1
// baseline (850.299 us; speedup 1.0000x reference)
//
#include <hip/hip_runtime.h>

#define NPOS (8 * 4096)   // 32768 positions
#define EMB 64
#define NBYTE 8
#define LAST 112
#define ODIM 512

// ---------------------------------------------------------------------------
// Prep: transpose highway + proj weights to [K][N] layout for coalesced reads.
//   wt1/wt2: [112][224]  wt[i*224+j] = hw_w[j*112+i]
//   pwt:     [112][512]  pwt[i*512+o] = proj_w[o*112+i]
// ---------------------------------------------------------------------------
__global__ void prep_kernel(const float* __restrict__ w1, const float* __restrict__ w2,
                            const float* __restrict__ pw,
                            float* __restrict__ wt1, float* __restrict__ wt2,
                            float* __restrict__ pwt) {
    int t = blockIdx.x * blockDim.x + threadIdx.x;
    if (t < 224 * 112) {
        int i = t / 224, j = t % 224;
        wt1[t] = w1[j * 112 + i];
        wt2[t] = w2[j * 112 + i];
    }
    if (t < 512 * 112) {
        int i = t / 512, o = t % 512;
        pwt[t] = pw[o * 112 + i];
    }
}

// ---------------------------------------------------------------------------
// Conv branch: one kernel per filter width (uniform work per lane, no
// divergence, no zero-padding waste). Thread = (local position, out channel).
// LDS holds the feature tile transposed to [pos][e][j] so the 8 taps for a
// given (pos,e) are 2 contiguous float4 broadcast reads.
//   y[oc,p] = sum_{e,k} feat[n, p+k, e] * w[oc,e,k] ; h = relu(max_p y + b)
// ---------------------------------------------------------------------------
template <int W, int C, int CHOFF, int PPB, int BS>
__global__ __launch_bounds__(BS) void conv_kernel(const float* __restrict__ feat,
                                                  const float* __restrict__ cw,
                                                  const float* __restrict__ cb,
                                                  float* __restrict__ h0) {
    __shared__ float xs[PPB * 512];
    const int t = threadIdx.x;
    const int pos0 = blockIdx.x * PPB;
    const int npos = (NPOS - pos0 < PPB) ? (NPOS - pos0) : PPB;

    // stage + transpose: xs[p][e*8+j] = feat[(pos0+p)*512 + j*64 + e]
    for (int idx = t; idx < npos * 512; idx += BS) {
        int p = idx >> 9;
        int r = idx & 511;
        int j = r >> 6;
        int e = r & 63;
        xs[p * 512 + e * 8 + j] = feat[(size_t)(pos0 + p) * 512 + r];
    }
    __syncthreads();

    const int pl = t / C;
    const int oc = t % C;
    if (pl < npos) {
        const int NP = 9 - W;   // number of valid output positions
        float acc[NP];
        const float bias = cb[oc];
#pragma unroll
        for (int p = 0; p < NP; ++p) acc[p] = bias;

        const float* wrow = cw + oc * 64 * W;   // [e][k] contiguous
        const float4* xr = (const float4*)(xs + pl * 512);
#pragma unroll 8
        for (int e = 0; e < 64; ++e) {
            float4 xa = xr[e * 2];
            float4 xb = xr[e * 2 + 1];
            float xj[8] = {xa.x, xa.y, xa.z, xa.w, xb.x, xb.y, xb.z, xb.w};
            float wk[W];
#pragma unroll
            for (int k = 0; k < W; ++k) wk[k] = wrow[e * W + k];
#pragma unroll
            for (int k = 0; k < W; ++k)
#pragma unroll
                for (int p = 0; p < NP; ++p)
                    acc[p] = fmaf(xj[p + k], wk[k], acc[p]);
        }
        float m = acc[0];
#pragma unroll
        for (int p = 1; p < NP; ++p) m = fmaxf(m, acc[p]);
        h0[(size_t)(pos0 + pl) * LAST + CHOFF + oc] = fmaxf(m, 0.f);
    }
}

// ---------------------------------------------------------------------------
// Highway layer, in-place on h. Block = 128 threads (112 active), P=16
// positions per block for weight reuse. h rows staged transposed in LDS
// ([i][p], padded row stride 20 floats for float4 alignment).
//   p = h @ W^T + b ; proj_x = p[:,:112], gate = p[:,112:]
//   h' = sigmoid(gate)*h + (1-sigmoid(gate))*relu(proj_x)
// ---------------------------------------------------------------------------
template <int P>
__global__ __launch_bounds__(128) void highway_kernel(float* __restrict__ h,
                                                      const float* __restrict__ wt,
                                                      const float* __restrict__ b) {
    __shared__ float ht[112 * 20];
    const int t = threadIdx.x;
    const int pos0 = blockIdx.x * P;

    for (int idx = t; idx < P * 112; idx += 128) {
        int p = idx / 112;
        int i = idx % 112;
        ht[i * 20 + p] = h[(size_t)(pos0 + p) * LAST + i];
    }
    __syncthreads();

    if (t < 112) {
        const int j = t;
        float px[P], gt[P];
        const float bp = b[j], bg = b[j + 112];
#pragma unroll
        for (int p = 0; p < P; ++p) { px[p] = bp; gt[p] = bg; }

        for (int i = 0; i < 112; ++i) {
            float wp = wt[i * 224 + j];          // coalesced across lanes
            float wg = wt[i * 224 + 112 + j];
            const float4* hr4 = (const float4*)(ht + i * 20);
            float4 ha = hr4[0], hb = hr4[1], hc = hr4[2], hd = hr4[3];
            float hv[16] = {ha.x, ha.y, ha.z, ha.w, hb.x, hb.y, hb.z, hb.w,
                            hc.x, hc.y, hc.z, hc.w, hd.x, hd.y, hd.z, hd.w};
#pragma unroll
            for (int p = 0; p < P; ++p) {
                px[p] = fmaf(hv[p], wp, px[p]);
                gt[p] = fmaf(hv[p], wg, gt[p]);
            }
        }
#pragma unroll
        for (int p = 0; p < P; ++p) {
            float g = 1.f / (1.f + __expf(-gt[p]));
            float hv = ht[j * 20 + p];
            float o = g * hv + (1.f - g) * fmaxf(px[p], 0.f);
            h[(size_t)(pos0 + p) * LAST + j] = o;
        }
    }
}

// ---------------------------------------------------------------------------
// Projection: out[n,o] = sum_i h[n,i]*proj_w[o,i] + pb[o]
// Block = 256 threads, each owns outputs {t, t+256} for P=16 positions.
// ---------------------------------------------------------------------------
template <int P>
__global__ __launch_bounds__(256) void proj_kernel(const float* __restrict__ h,
                                                   const float* __restrict__ pwt,
                                                   const float* __restrict__ pb,
                                                   float* __restrict__ out) {
    __shared__ float ht[112 * 20];
    const int t = threadIdx.x;
    const int pos0 = blockIdx.x * P;

    for (int idx = t; idx < P * 112; idx += 256) {
        int p = idx / 112;
        int i = idx % 112;
        ht[i * 20 + p] = h[(size_t)(pos0 + p) * LAST + i];
    }
    __syncthreads();

    const int o = t;
    float a0[P], a1[P];
#pragma unroll
    for (int p = 0; p < P; ++p) { a0[p] = 0.f; a1[p] = 0.f; }

    for (int i = 0; i < 112; ++i) {
        float w0 = pwt[i * 512 + o];             // coalesced across lanes
        float w1 = pwt[i * 512 + o + 256];
        const float4* hr4 = (const float4*)(ht + i * 20);
        float4 ha = hr4[0], hb = hr4[1], hc = hr4[2], hd = hr4[3];
        float hv[16] = {ha.x, ha.y, ha.z, ha.w, hb.x, hb.y, hb.z, hb.w,
                        hc.x, hc.y, hc.z, hc.w, hd.x, hd.y, hd.z, hd.w};
#pragma unroll
        for (int p = 0; p < P; ++p) {
            a0[p] = fmaf(hv[p], w0, a0[p]);
            a1[p] = fmaf(hv[p], w1, a1[p]);
        }
    }
    const float b0 = pb[o], b1 = pb[o + 256];
#pragma unroll
    for (int p = 0; p < P; ++p) {
        out[(size_t)(pos0 + p) * ODIM + o] = a0[p] + b0;
        out[(size_t)(pos0 + p) * ODIM + o + 256] = a1[p] + b1;
    }
}

// ---------------------------------------------------------------------------
extern "C" void kernel_launch(void* const* d_in, const int* in_sizes, int n_in,
                              void* d_out, int out_size, void* d_ws, size_t ws_size,
                              hipStream_t stream) {
    // setup_inputs() dict order: features, (conv_w1, conv_b1), ..., (conv_w7, conv_b7),
    //                            hw_w1, hw_b1, hw_w2, hw_b2, proj_w, proj_b
    const float* feat = (const float*)d_in[0];
    const float* cw[7];
    const float* cb[7];
    for (int f = 0; f < 7; ++f) {
        cw[f] = (const float*)d_in[1 + 2 * f];
        cb[f] = (const float*)d_in[2 + 2 * f];
    }
    const float* hw_w1 = (const float*)d_in[15];
    const float* hw_b1 = (const float*)d_in[16];
    const float* hw_w2 = (const float*)d_in[17];
    const float* hw_b2 = (const float*)d_in[18];
    const float* pw    = (const float*)d_in[19];
    const float* pb    = (const float*)d_in[20];
    float* out = (float*)d_out;

    char* ws = (char*)d_ws;
    float* h0  = (float*)ws;                         // 32768*112 fp32 = 14,680,064 B
    float* wt1 = (float*)(ws + 14680064);            // 25088 fp32
    float* wt2 = wt1 + 25088;                        // 25088 fp32
    float* pwt = wt2 + 25088;                        // 57344 fp32

    prep_kernel<<<224, 256, 0, stream>>>(hw_w1, hw_w2, pw, wt1, wt2, pwt);

    // filters: (W, C, CHOFF, PPB, BS=PPB*C), grid = ceil(32768/PPB)
    conv_kernel<1, 4, 0, 16, 64><<<2048, 64, 0, stream>>>(feat, cw[0], cb[0], h0);
    conv_kernel<2, 8, 4, 16, 128><<<2048, 128, 0, stream>>>(feat, cw[1], cb[1], h0);
    conv_kernel<3, 12, 12, 16, 192><<<2048, 192, 0, stream>>>(feat, cw[2], cb[2], h0);
    conv_kernel<4, 16, 24, 16, 256><<<2048, 256, 0, stream>>>(feat, cw[3], cb[3], h0);
    conv_kernel<5, 20, 40, 12, 240><<<2731, 240, 0, stream>>>(feat, cw[4], cb[4], h0);
    conv_kernel<6, 24, 60, 10, 240><<<3277, 240, 0, stream>>>(feat, cw[5], cb[5], h0);
    conv_kernel<7, 28, 84, 9, 252><<<3641, 252, 0, stream>>>(feat, cw[6], cb[6], h0);

    highway_kernel<16><<<2048, 128, 0, stream>>>(h0, wt1, hw_b1);
    highway_kernel<16><<<2048, 128, 0, stream>>>(h0, wt2, hw_b2);

    proj_kernel<16><<<2048, 256, 0, stream>>>(h0, pwt, pb, out);
}

// Round 3
// 202.003 us; speedup vs baseline: 4.2093x; 4.2093x over previous
//
#include <hip/hip_runtime.h>

typedef __attribute__((ext_vector_type(8))) short short8;
typedef __attribute__((ext_vector_type(4))) float f32x4;

#define NPOS 32768
#define KDIM 512
#define NCT  30          // conv n-tiles (480 padded cols)
#define CHUNK_BYTES 30720 // one K-chunk (32 k) of conv B in frag order

// ---- bf16 helpers (RNE) ----
__device__ __forceinline__ unsigned short f2bf(float x) {
    unsigned u = __float_as_uint(x);
    return (unsigned short)((u + 0x7FFFu + ((u >> 16) & 1u)) >> 16);
}
__device__ __forceinline__ float bf2f(unsigned short h) {
    return __uint_as_float(((unsigned)h) << 16);
}

// ---- async global->LDS 16B stage: g is per-lane, l is wave-uniform base ----
__device__ __forceinline__ void stage16(const void* g, void* l, int lane) {
    __builtin_amdgcn_global_load_lds(
        (const __attribute__((address_space(1))) unsigned int*)g,
        (__attribute__((address_space(3))) unsigned int*)l, 16, 0, 0);
}

// ===========================================================================
// Prep: swizzle all weights into MFMA B-fragment order (bf16).
// B-frag (16x16x32): lane l holds B[k0 + (l>>4)*8 + i][n0 + (l&15)], i=0..7.
// Conv B: 512 x 480 banded; col blocks (pad to 16): f1@0(32) f2@32(64)
// f3@96(80) f4@176(80) f5@256(80) f6@336(80) f7@416(64). col=FB+oc*NP+p.
// ===========================================================================
__global__ void prep_kernel(const float* __restrict__ w1, const float* __restrict__ w2,
                            const float* __restrict__ w3, const float* __restrict__ w4,
                            const float* __restrict__ w5, const float* __restrict__ w6,
                            const float* __restrict__ w7, const float* __restrict__ hw1,
                            const float* __restrict__ hw2, const float* __restrict__ pw,
                            unsigned short* __restrict__ WC, unsigned short* __restrict__ W1s,
                            unsigned short* __restrict__ W2s, unsigned short* __restrict__ Ps) {
    int gid = blockIdx.x * 256 + threadIdx.x;
    if (gid < 245760) {                      // conv: 512*480
        int k = gid / 480, col = gid % 480;
        const float* wp; int cbnd, NP, C, W;
        if (col < 32)       { wp = w1; cbnd = 0;   NP = 8; C = 4;  W = 1; }
        else if (col < 96)  { wp = w2; cbnd = 32;  NP = 7; C = 8;  W = 2; }
        else if (col < 176) { wp = w3; cbnd = 96;  NP = 6; C = 12; W = 3; }
        else if (col < 256) { wp = w4; cbnd = 176; NP = 5; C = 16; W = 4; }
        else if (col < 336) { wp = w5; cbnd = 256; NP = 4; C = 20; W = 5; }
        else if (col < 416) { wp = w6; cbnd = 336; NP = 3; C = 24; W = 6; }
        else                { wp = w7; cbnd = 416; NP = 2; C = 28; W = 7; }
        int c2 = col - cbnd, oc = c2 / NP, p = c2 - oc * NP;
        int j = k >> 6, e = k & 63, dk = j - p;
        float v = 0.f;
        if (oc < C && dk >= 0 && dk < W) v = wp[(oc * 64 + e) * W + dk];
        int q = k >> 5, kr = k & 31;
        WC[((q * NCT + (col >> 4)) * 64 + ((kr >> 3) * 16 + (col & 15))) * 8 + (kr & 7)] = f2bf(v);
    } else if (gid < 245760 + 57344) {       // highway: 2 x (128*224)
        int x = gid - 245760;
        const float* src = (x < 28672) ? hw1 : hw2;
        unsigned short* dst = (x < 28672) ? W1s : W2s;
        if (x >= 28672) x -= 28672;          // (was a bogus &28671 "mod")
        int k = x / 224, n = x % 224;
        float v = (k < 112) ? src[n * 112 + k] : 0.f;
        int q = k >> 5, kr = k & 31;
        dst[((q * 14 + (n >> 4)) * 64 + ((kr >> 3) * 16 + (n & 15))) * 8 + (kr & 7)] = f2bf(v);
    } else if (gid < 245760 + 57344 + 65536) { // proj: 128*512
        int x = gid - 303104;
        int k = x / 512, n = x % 512;
        float v = (k < 112) ? pw[n * 112 + k] : 0.f;
        int q = k >> 5, kr = k & 31;
        Ps[((q * 32 + (n >> 4)) * 64 + ((kr >> 3) * 16 + (n & 15))) * 8 + (kr & 7)] = f2bf(v);
    }
}

// ===========================================================================
// Conv GEMM: [32768,512]x[512,480] bf16 MFMA, fused max/bias/relu epilogue.
// Block: 256 thr / 4 waves, 64 rows (wave w owns rows w*16..+15).
// A-frags in registers (16 k-chunks); B double-buffered via global_load_lds.
// ===========================================================================
template <int T0, int NT>
__device__ __forceinline__ void dump_phase(float* Cb, const f32x4* acc, int wave, int lane) {
    int r0 = wave * 16 + ((lane >> 4) * 4);
    int c0 = lane & 15;
#pragma unroll
    for (int tt = 0; tt < NT; ++tt)
#pragma unroll
        for (int r = 0; r < 4; ++r)
            Cb[(r0 + r) * 161 + tt * 16 + c0] = acc[T0 + tt][r];
}

__device__ void reduce_phase(const float* Cb, unsigned short* ht, int tid,
                             int cA, int NPA, int choffA, int colbA, const float* cbA,
                             int cB, int NPB, int choffB, int colbB, const float* cbB) {
    int noc = cA + cB;
    for (int idx = tid; idx < 64 * noc; idx += 256) {
        int row = idx & 63, ocp = idx >> 6;
        bool isB = ocp >= cA;
        int oc = isB ? ocp - cA : ocp;
        int NP = isB ? NPB : NPA;
        int colb = isB ? colbB : colbA;
        int choff = isB ? choffB : choffA;
        const float* cb = isB ? cbB : cbA;
        const float* src = Cb + row * 161 + colb + oc * NP;
        float m = src[0];
        for (int k = 1; k < NP; ++k) m = fmaxf(m, src[k]);
        float v = fmaxf(m + cb[oc], 0.f);
        ht[row * 128 + choff + oc] = f2bf(v);
    }
}

__global__ __launch_bounds__(256, 2) void conv_gemm(
        const float* __restrict__ feat, const unsigned short* __restrict__ WC,
        const float* cb0, const float* cb1, const float* cb2, const float* cb3,
        const float* cb4, const float* cb5, const float* cb6,
        unsigned short* __restrict__ hg) {
    __shared__ __align__(16) char sm[61440];
    const int tid = threadIdx.x, lane = tid & 63, wave = tid >> 6;
    const int c0 = lane & 15, kq = lane >> 4;
    const int m0 = blockIdx.x * 64;

    // A fragments: 16 k-chunks, fp32 -> bf16 in registers
    const float* arow = feat + (size_t)(m0 + wave * 16 + c0) * KDIM + kq * 8;
    short8 af[16];
#pragma unroll
    for (int q = 0; q < 16; ++q) {
        float t[8];
        *(float4*)(t)     = *(const float4*)(arow + q * 32);
        *(float4*)(t + 4) = *(const float4*)(arow + q * 32 + 4);
        short8 v;
#pragma unroll
        for (int i = 0; i < 8; ++i) v[i] = (short)f2bf(t[i]);
        af[q] = v;
    }

    f32x4 zero = {0.f, 0.f, 0.f, 0.f};
    f32x4 acc[NCT];
#pragma unroll
    for (int t = 0; t < NCT; ++t) acc[t] = zero;

    // prologue: stage chunk 0 into buf 0
    for (int i = tid; i < 1920; i += 256)
        stage16(WC + i * 8, sm + (i - lane) * 16, lane);

#pragma unroll
    for (int q = 0; q < 16; ++q) {
        __syncthreads();
        if (q < 15) {
            const unsigned short* src = WC + (q + 1) * (CHUNK_BYTES / 2);
            char* dst = sm + ((q + 1) & 1) * CHUNK_BYTES;
            for (int i = tid; i < 1920; i += 256)
                stage16(src + i * 8, dst + (i - lane) * 16, lane);
        }
        const char* bb = sm + (q & 1) * CHUNK_BYTES;
#pragma unroll
        for (int t = 0; t < NCT; ++t) {
            short8 b = *(const short8*)(bb + (t * 64 + lane) * 16);
            acc[t] = __builtin_amdgcn_mfma_f32_16x16x32_bf16(af[q], b, acc[t], 0, 0, 0);
        }
    }

    // Epilogue: phased through LDS (phases aligned to filter boundaries)
    float* Cb = (float*)sm;
    unsigned short* ht = (unsigned short*)(sm + 41216);
    __syncthreads();
    for (int i = tid; i < 1024; i += 256)            // zero K-pad cols 112..127
        ht[(i >> 4) * 128 + 112 + (i & 15)] = 0;
    dump_phase<0, 6>(Cb, acc, wave, lane);
    __syncthreads();
    reduce_phase(Cb, ht, tid, 4, 8, 0, 0, cb0, 8, 7, 4, 32, cb1);
    __syncthreads();
    dump_phase<6, 10>(Cb, acc, wave, lane);
    __syncthreads();
    reduce_phase(Cb, ht, tid, 12, 6, 12, 0, cb2, 16, 5, 24, 80, cb3);
    __syncthreads();
    dump_phase<16, 10>(Cb, acc, wave, lane);
    __syncthreads();
    reduce_phase(Cb, ht, tid, 20, 4, 40, 0, cb4, 24, 3, 60, 80, cb5);
    __syncthreads();
    dump_phase<26, 4>(Cb, acc, wave, lane);
    __syncthreads();
    reduce_phase(Cb, ht, tid, 28, 2, 84, 0, cb6, 0, 1, 0, 0, cb6);
    __syncthreads();
    uint4* dst = (uint4*)(hg + (size_t)m0 * 128);
    for (int i = tid; i < 1024; i += 256) dst[i] = ((const uint4*)ht)[i];
}

// ===========================================================================
// Tail: highway1 -> highway2 -> proj fused; h stays in LDS between stages.
// ===========================================================================
__global__ __launch_bounds__(256, 2) void tail_kernel(
        const unsigned short* __restrict__ hg, const unsigned short* __restrict__ W1,
        const unsigned short* __restrict__ W2, const unsigned short* __restrict__ PW,
        const float* __restrict__ hb1, const float* __restrict__ hb2,
        const float* __restrict__ pb, float* __restrict__ out) {
    __shared__ __align__(16) char sm[65536];
    const int tid = threadIdx.x, lane = tid & 63, wave = tid >> 6;
    const int c0 = lane & 15, kq = lane >> 4;
    const int m0 = blockIdx.x * 64;
    f32x4 zero = {0.f, 0.f, 0.f, 0.f};

    // A2 frags from global h
    short8 a2[4];
#pragma unroll
    for (int q = 0; q < 4; ++q)
        a2[q] = *(const short8*)(hg + (size_t)(m0 + wave * 16 + c0) * 128 + q * 32 + kq * 8);

    // GEMM2 (highway1): stage full W1 (57344 B)
    for (int i = tid; i < 3584; i += 256)
        stage16(W1 + i * 8, sm + (i - lane) * 16, lane);
    __syncthreads();
    f32x4 acc2[14];
#pragma unroll
    for (int t = 0; t < 14; ++t) acc2[t] = zero;
#pragma unroll
    for (int t = 0; t < 14; ++t)
#pragma unroll
        for (int q = 0; q < 4; ++q) {
            short8 b = *(const short8*)(sm + ((q * 14 + t) * 64 + lane) * 16);
            acc2[t] = __builtin_amdgcn_mfma_f32_16x16x32_bf16(a2[q], b, acc2[t], 0, 0, 0);
        }
    __syncthreads();   // all W1 reads done before region reuse

    // epilogue2 -> htile (stride 136 bf16; all accesses wave-local rows)
    unsigned short* ht = (unsigned short*)sm;
#pragma unroll
    for (int t = 0; t < 7; ++t) {
        float bp = hb1[t * 16 + c0], bg = hb1[112 + t * 16 + c0];
#pragma unroll
        for (int r = 0; r < 4; ++r) {
            int row = wave * 16 + kq * 4 + r;
            int col = t * 16 + c0;
            float px = acc2[t][r] + bp;
            float gt = acc2[t + 7][r] + bg;
            float g = 1.f / (1.f + __expf(-gt));
            float hres = bf2f(hg[(size_t)(m0 + row) * 128 + col]);
            ht[row * 136 + col] = f2bf(g * hres + (1.f - g) * fmaxf(px, 0.f));
        }
    }
    for (int z = lane; z < 256; z += 64)             // zero own-wave K-pad
        ht[(wave * 16 + (z >> 4)) * 136 + 112 + (z & 15)] = 0;

    short8 a3[4];
#pragma unroll
    for (int q = 0; q < 4; ++q)
        a3[q] = *(const short8*)((const char*)ht + (wave * 16 + c0) * 272 + q * 64 + kq * 16);

    // GEMM3 (highway2): B staged in two 28KB halves at sm+17408
    char* wbuf = sm + 17408;
    f32x4 acc3[14];
#pragma unroll
    for (int t = 0; t < 14; ++t) acc3[t] = zero;
    for (int i = tid; i < 1792; i += 256)
        stage16(W2 + i * 8, wbuf + (i - lane) * 16, lane);
    __syncthreads();
#pragma unroll
    for (int t = 0; t < 14; ++t)
#pragma unroll
        for (int q = 0; q < 2; ++q) {
            short8 b = *(const short8*)(wbuf + ((q * 14 + t) * 64 + lane) * 16);
            acc3[t] = __builtin_amdgcn_mfma_f32_16x16x32_bf16(a3[q], b, acc3[t], 0, 0, 0);
        }
    __syncthreads();   // first-half reads done before restaging same buffer (race fix)
    for (int i = tid; i < 1792; i += 256)
        stage16(W2 + 14336 + i * 8, wbuf + (i - lane) * 16, lane);
    __syncthreads();
#pragma unroll
    for (int t = 0; t < 14; ++t)
#pragma unroll
        for (int q = 0; q < 2; ++q) {
            short8 b = *(const short8*)(wbuf + ((q * 14 + t) * 64 + lane) * 16);
            acc3[t] = __builtin_amdgcn_mfma_f32_16x16x32_bf16(a3[2 + q], b, acc3[t], 0, 0, 0);
        }

    // epilogue3 -> htile in place (same thread reads residual then writes)
#pragma unroll
    for (int t = 0; t < 7; ++t) {
        float bp = hb2[t * 16 + c0], bg = hb2[112 + t * 16 + c0];
#pragma unroll
        for (int r = 0; r < 4; ++r) {
            int row = wave * 16 + kq * 4 + r;
            int col = t * 16 + c0;
            float px = acc3[t][r] + bp;
            float gt = acc3[t + 7][r] + bg;
            float g = 1.f / (1.f + __expf(-gt));
            float hres = bf2f(ht[row * 136 + col]);
            ht[row * 136 + col] = f2bf(g * hres + (1.f - g) * fmaxf(px, 0.f));
        }
    }

    short8 a4[4];
#pragma unroll
    for (int q = 0; q < 4; ++q)
        a4[q] = *(const short8*)((const char*)ht + (wave * 16 + c0) * 272 + q * 64 + kq * 16);

    // GEMM4 (proj): B streamed in 32KB chunks
    f32x4 acc4[32];
#pragma unroll
    for (int t = 0; t < 32; ++t) acc4[t] = zero;
#pragma unroll
    for (int q = 0; q < 4; ++q) {
        __syncthreads();
        for (int i = tid; i < 2048; i += 256)
            stage16(PW + q * 16384 + i * 8, wbuf + (i - lane) * 16, lane);
        __syncthreads();
#pragma unroll
        for (int t = 0; t < 32; ++t) {
            short8 b = *(const short8*)(wbuf + (t * 64 + lane) * 16);
            acc4[t] = __builtin_amdgcn_mfma_f32_16x16x32_bf16(a4[q], b, acc4[t], 0, 0, 0);
        }
    }

    // epilogue4: +bias, coalesced store via LDS transpose (2 halves of 256 cols)
    float* ot = (float*)sm;
#pragma unroll
    for (int half = 0; half < 2; ++half) {
        __syncthreads();
#pragma unroll
        for (int t16 = 0; t16 < 16; ++t16) {
            int col = (half * 16 + t16) * 16 + c0;
            float b = pb[col];
#pragma unroll
            for (int r = 0; r < 4; ++r)
                ot[(wave * 16 + kq * 4 + r) * 256 + t16 * 16 + c0] = acc4[half * 16 + t16][r] + b;
        }
        __syncthreads();
        for (int i = tid; i < 4096; i += 256) {
            int row = i >> 6, c = i & 63;
            *(float4*)(out + (size_t)(m0 + row) * 512 + half * 256 + c * 4) = ((const float4*)ot)[i];
        }
    }
}

// ===========================================================================
extern "C" void kernel_launch(void* const* d_in, const int* in_sizes, int n_in,
                              void* d_out, int out_size, void* d_ws, size_t ws_size,
                              hipStream_t stream) {
    const float* feat = (const float*)d_in[0];
    const float* cw[7];
    const float* cb[7];
    for (int f = 0; f < 7; ++f) {
        cw[f] = (const float*)d_in[1 + 2 * f];
        cb[f] = (const float*)d_in[2 + 2 * f];
    }
    const float* hw_w1 = (const float*)d_in[15];
    const float* hw_b1 = (const float*)d_in[16];
    const float* hw_w2 = (const float*)d_in[17];
    const float* hw_b2 = (const float*)d_in[18];
    const float* pw    = (const float*)d_in[19];
    const float* pb    = (const float*)d_in[20];
    float* out = (float*)d_out;

    char* ws = (char*)d_ws;
    unsigned short* WC  = (unsigned short*)ws;                  // 491,520 B
    unsigned short* W1s = (unsigned short*)(ws + 491520);       //  57,344 B
    unsigned short* W2s = (unsigned short*)(ws + 548864);       //  57,344 B
    unsigned short* Ps  = (unsigned short*)(ws + 606208);       // 131,072 B
    unsigned short* hg  = (unsigned short*)(ws + 737280);       // 8,388,608 B

    prep_kernel<<<1440, 256, 0, stream>>>(cw[0], cw[1], cw[2], cw[3], cw[4], cw[5], cw[6],
                                          hw_w1, hw_w2, pw, WC, W1s, W2s, Ps);
    conv_gemm<<<512, 256, 0, stream>>>(feat, WC, cb[0], cb[1], cb[2], cb[3], cb[4], cb[5], cb[6], hg);
    tail_kernel<<<512, 256, 0, stream>>>(hg, W1s, W2s, Ps, hw_b1, hw_b2, pb, out);
}